// Round 4
// baseline (2589.726 us; speedup 1.0000x reference)
//
#include <hip/hip_runtime.h>
#include <math.h>

// Problem constants
#define B_  4096
#define L_  60
#define I_  13
#define H_  128
#define AHP 136            // h-tile pitch in halfs (272B rows: 16B-aligned, odd 16B-groups)

typedef _Float16 half8 __attribute__((ext_vector_type(8)));
typedef _Float16 half4v __attribute__((ext_vector_type(4)));
typedef float float4v __attribute__((ext_vector_type(4)));

// ---------------------------------------------------------------------------
// Unified weight pack, B-fragment order for mfma_f32_16x16x32_f16.
// k-tiles: [0,XT) from w_ih (zero-pad k>=KIH), [XT,NT) from w_hh.
// Element e = (((kt*4 + w4)*8 + ct)*64 + l)*8 + j ->
//   B[k = kt*32+(l>>4)*8+j][n = (ct>>1)*128 + w4*32 + (ct&1)*16 + (l&15)]
// ---------------------------------------------------------------------------
__global__ void pack_kernel(const float* __restrict__ ih, const float* __restrict__ hh,
                            int KIH, int XT, int n, _Float16* __restrict__ dst,
                            const float* __restrict__ bih, const float* __restrict__ bhh,
                            float* __restrict__ bias_out) {
    int g0 = blockIdx.x * blockDim.x + threadIdx.x;
    for (int e = g0; e < n; e += gridDim.x * blockDim.x) {
        int j  = e & 7;
        int l  = (e >> 3) & 63;
        int ct = (e >> 9) & 7;
        int w4 = (e >> 12) & 3;
        int kt = e >> 14;
        int nn = (ct >> 1) * 128 + w4 * 32 + (ct & 1) * 16 + (l & 15);
        int kq = ((l >> 4) << 3) + j;
        _Float16 v;
        if (kt < XT) {
            int k = kt * 32 + kq;
            v = (k < KIH) ? (_Float16)ih[nn * KIH + k] : (_Float16)0.f;
        } else {
            int k = (kt - XT) * 32 + kq;
            v = (_Float16)hh[nn * H_ + k];
        }
        dst[e] = v;
    }
    if (g0 < 512) bias_out[g0] = bih[g0] + bhh[g0];
}

__device__ __forceinline__ float sigm(float x) { return 1.f / (1.f + __expf(-x)); }
__device__ __forceinline__ float tanh_f(float x) { return 1.f - 2.f / (__expf(2.f * x) + 1.f); }

// LDS (halfs): RBUF f32[16384] = [0,32768) ; AHm [32768, 32768+4352) ; AX0 [37120, 38144)
#define SMEM_BYTES (38144 * 2)   // 76288

// MFMA tile sweep for tiles [T0,T1): A from AX0 (L0 x), global yin, or LDS h-tile.
template <int T0, int T1, int XT, int IS_L0>
__device__ __forceinline__ void do_tiles(float4v (&acc0)[8], float4v (&acc1)[8],
                                         const _Float16* __restrict__ yr0,
                                         const _Float16* __restrict__ yr1,
                                         const _Float16* __restrict__ h0,
                                         const _Float16* __restrict__ h1,
                                         const _Float16* __restrict__ ax,
                                         const _Float16* __restrict__ pWl) {
#pragma unroll
    for (int ti = T0; ti < T1; ++ti) {
        half8 a0, a1;
        if (ti < XT) {
            if (IS_L0) { a0 = *(const half8*)(ax);            a1 = *(const half8*)(ax + 512); }
            else       { a0 = *(const half8*)(yr0 + ti * 32); a1 = *(const half8*)(yr1 + ti * 32); }
        } else {
            a0 = *(const half8*)(h0 + (ti - XT) * 32);
            a1 = *(const half8*)(h1 + (ti - XT) * 32);
        }
#pragma unroll
        for (int ct = 0; ct < 8; ++ct) {
            half8 b = *(const half8*)(pWl + ti * 16384 + ct * 512);
            acc0[ct] = __builtin_amdgcn_mfma_f32_16x16x32_f16(a0, b, acc0[ct], 0, 0, 0);
            acc1[ct] = __builtin_amdgcn_mfma_f32_16x16x32_f16(a1, b, acc1[ct], 0, 0, 0);
        }
    }
}

// ---------------------------------------------------------------------------
// Persistent BiLSTM layer, MFMA f16, 512 threads = 8 waves (2/SIMD).
// Block = 32 batch rows x 1 direction. Wave (w4, half): w4 owns n-cols
// [w4*32, w4*32+32) x 4 gates (ct 0..7); wave-pair (w, w^4) k-splits the
// NT tiles at SPLIT; partials exchanged via fp32 LDS RBUF (1 extra rd/wr,
// same 2 barriers/step). Pointwise split by row-tile: wave does rt = half.
// All weights (w_ih|w_hh unified pack) streamed from L2 every step.
// ---------------------------------------------------------------------------
template <int XT, int NT, int SPLIT, int IS_L0>
__global__ __launch_bounds__(512, 2)
void lstm_mfma(const float* __restrict__ x0, const _Float16* __restrict__ yin,
               const _Float16* __restrict__ pW_f, const _Float16* __restrict__ pW_b,
               const float* __restrict__ bias_f, const float* __restrict__ bias_b,
               _Float16* __restrict__ yout)
{
    extern __shared__ _Float16 sm[];
    float*    RBUF = (float*)sm;           // 64KB: [wave][ct][lane] f32x4
    _Float16* AHm  = sm + 32768;           // 32 x AHP halfs
    _Float16* AX0  = sm + 32768 + 4352;    // 1024 halfs (L0 x-tile staging)

    const int tid  = threadIdx.x;
    const int lane = tid & 63;
    const int w    = tid >> 6;      // 0..7
    const int w4   = w & 3;
    const int half = w >> 2;
    const int dir  = blockIdx.x & 1;
    const int rb   = (blockIdx.x >> 1) * 32;
    const int m    = lane & 15;
    const int q    = lane >> 4;

    const _Float16* __restrict__ pW   = dir ? pW_b : pW_f;
    const float*    __restrict__ bias = dir ? bias_b : bias_f;
    const _Float16* __restrict__ pWl  = pW + w4 * 4096 + lane * 8;

    for (int i = tid; i < 32 * AHP; i += 512) AHm[i] = (_Float16)0.f;

    float bv[8];
#pragma unroll
    for (int ct = 0; ct < 8; ++ct)
        bv[ct] = bias[(ct >> 1) * 128 + w4 * 32 + (ct & 1) * 16 + m];

    float cst[2][4];
#pragma unroll
    for (int u = 0; u < 2; ++u)
#pragma unroll
        for (int r = 0; r < 4; ++r) cst[u][r] = 0.f;

    const int rown0 = half * 16 + q * 4;   // pointwise row base (own rt = half)

    for (int s = 0; s < L_; ++s) {
        const int t = dir ? (L_ - 1 - s) : s;

        if (IS_L0 && tid < 256) {
            // Stage layer-0 x into A-frag order (1024 halfs, zero-pad k>=13).
            const int e  = tid * 4;
            const int j0 = e & 7;
            const int ln = (e >> 3) & 63;
            const int rt = e >> 9;
            const int row = rt * 16 + (ln & 15);
            const int kb  = ((ln >> 4) << 3) + j0;
            const float* xr = x0 + (size_t)(rb + row) * (L_ * I_) + t * I_;
            half4v tmp;
#pragma unroll
            for (int jj = 0; jj < 4; ++jj) {
                int k = kb + jj;
                tmp[jj] = (k < I_) ? (_Float16)xr[k] : (_Float16)0.f;
            }
            ((half4v*)AX0)[tid] = tmp;
        }

        __syncthreads();   // (A) h(t-1) ready, AX0 staged, RBUF free

        float4v acc0[8], acc1[8];
#pragma unroll
        for (int ct = 0; ct < 8; ++ct) { acc0[ct] = (float4v){0,0,0,0}; acc1[ct] = (float4v){0,0,0,0}; }

        const _Float16* yr0 = nullptr; const _Float16* yr1 = nullptr;
        if (!IS_L0) {
            yr0 = yin + (size_t)(rb + m) * 15360 + t * 256 + q * 8;
            yr1 = yr0 + (size_t)16 * 15360;
        }
        const _Float16* h0 = AHm + m * AHP + q * 8;
        const _Float16* h1 = AHm + (16 + m) * AHP + q * 8;
        const _Float16* ax = AX0 + lane * 8;

        if (half == 0) do_tiles<0, SPLIT, XT, IS_L0>(acc0, acc1, yr0, yr1, h0, h1, ax, pWl);
        else           do_tiles<SPLIT, NT, XT, IS_L0>(acc0, acc1, yr0, yr1, h0, h1, ax, pWl);

        // Write partial for the row-tile we do NOT own (wave-uniform branch,
        // static register indexing only).
        float4v* RB4 = (float4v*)RBUF;
        if (half == 0) {
#pragma unroll
            for (int ct = 0; ct < 8; ++ct) RB4[(w * 8 + ct) * 64 + lane] = acc1[ct];
        } else {
#pragma unroll
            for (int ct = 0; ct < 8; ++ct) RB4[(w * 8 + ct) * 64 + lane] = acc0[ct];
        }

        __syncthreads();   // (B) partials visible; all A-frag LDS reads done

        float4v S[8];
        if (half == 0) {
#pragma unroll
            for (int ct = 0; ct < 8; ++ct) S[ct] = acc0[ct] + RB4[((w ^ 4) * 8 + ct) * 64 + lane];
        } else {
#pragma unroll
            for (int ct = 0; ct < 8; ++ct) S[ct] = acc1[ct] + RB4[((w ^ 4) * 8 + ct) * 64 + lane];
        }

        // Pointwise LSTM cell (i,f,g,o) for own row-tile: 8 elems/thread.
#pragma unroll
        for (int u = 0; u < 2; ++u)
#pragma unroll
            for (int r = 0; r < 4; ++r) {
                const float gi = S[0 + u][r] + bv[0 + u];
                const float gf = S[2 + u][r] + bv[2 + u];
                const float gg = S[4 + u][r] + bv[4 + u];
                const float go = S[6 + u][r] + bv[6 + u];
                const float cc = sigm(gf) * cst[u][r] + sigm(gi) * tanh_f(gg);
                cst[u][r] = cc;
                const float hh = sigm(go) * tanh_f(cc);
                const int row = rown0 + r;
                const int j   = w4 * 32 + u * 16 + m;
                AHm[row * AHP + j] = (_Float16)hh;
                yout[(size_t)(rb + row) * 15360 + t * 256 + dir * H_ + j] = (_Float16)hh;
            }
    }
}

// ---------------------------------------------------------------------------
// Final: out[b][o] = b_out[o] + sum relu(y3[b][:]) * w_out[o][:]
// ---------------------------------------------------------------------------
__global__ __launch_bounds__(256)
void final_kernel(const _Float16* __restrict__ y, const float* __restrict__ wout,
                  const float* __restrict__ bout, float* __restrict__ outp, int nrows) {
    const int wid  = (blockIdx.x * blockDim.x + threadIdx.x) >> 6;
    const int lane = threadIdx.x & 63;
    if (wid >= nrows) return;
    const half8*  __restrict__ y8 = (const half8*)(y + (size_t)wid * 15360);
    const float4* __restrict__ w4 = (const float4*)wout;   // [2][3840]
    float s0 = 0.f, s1 = 0.f;
#pragma unroll 2
    for (int it = 0; it < 30; ++it) {
        const int idx = it * 64 + lane;
        half8 h = y8[idx];
        float v[8];
#pragma unroll
        for (int e = 0; e < 8; ++e) v[e] = fmaxf((float)h[e], 0.f);
        const float4 a0 = w4[idx * 2], a1 = w4[idx * 2 + 1];
        const float4 b0 = w4[3840 + idx * 2], b1 = w4[3840 + idx * 2 + 1];
        s0 += v[0] * a0.x + v[1] * a0.y + v[2] * a0.z + v[3] * a0.w
            + v[4] * a1.x + v[5] * a1.y + v[6] * a1.z + v[7] * a1.w;
        s1 += v[0] * b0.x + v[1] * b0.y + v[2] * b0.z + v[3] * b0.w
            + v[4] * b1.x + v[5] * b1.y + v[6] * b1.z + v[7] * b1.w;
    }
#pragma unroll
    for (int off = 32; off > 0; off >>= 1) {
        s0 += __shfl_down(s0, off);
        s1 += __shfl_down(s1, off);
    }
    if (lane == 0) {
        outp[wid * 2 + 0] = s0 + bout[0];
        outp[wid * 2 + 1] = s1 + bout[1];
    }
}

// ---------------------------------------------------------------------------
extern "C" void kernel_launch(void* const* d_in, const int* in_sizes, int n_in,
                              void* d_out, int out_size, void* d_ws, size_t ws_size,
                              hipStream_t stream) {
    const float* x = (const float*)d_in[0];
    auto W = [&](int l, int d, int which) { return (const float*)d_in[1 + l * 8 + d * 4 + which]; };
    const float* w_out = (const float*)d_in[25];
    const float* b_out = (const float*)d_in[26];

    // Workspace: unified packs (halfs), fp32 bias, fp16 y ping-pong buffers.
    _Float16* wsH = (_Float16*)d_ws;
    const size_t p0f = 0,      p0b = 81920;    // L0: NT=5  -> 81920 halfs each
    const size_t p1f = 163840, p1b = 360448;   // L1: NT=12 -> 196608 halfs each
    const size_t p2f = 557056, p2b = 753664;   // L2: NT=12
    const size_t packs_end = 950272;
    float* bias = (float*)(wsH + packs_end);   // 6*512 fp32 (pad to 3072+1024)
    const size_t head_bytes = packs_end * 2 + 4096 * 4;
    _Float16* y0 = (_Float16*)((char*)d_ws + head_bytes);

    hipFuncSetAttribute((const void*)lstm_mfma<1, 5, 3, 1>,  hipFuncAttributeMaxDynamicSharedMemorySize, SMEM_BYTES);
    hipFuncSetAttribute((const void*)lstm_mfma<8, 12, 6, 0>, hipFuncAttributeMaxDynamicSharedMemorySize, SMEM_BYTES);

    // ---- weight packing (+ bias combine) ----
    pack_kernel<<<320, 256, 0, stream>>>(W(0,0,0), W(0,0,1), I_,  1, 81920,  wsH + p0f, W(0,0,2), W(0,0,3), bias + 0);
    pack_kernel<<<320, 256, 0, stream>>>(W(0,1,0), W(0,1,1), I_,  1, 81920,  wsH + p0b, W(0,1,2), W(0,1,3), bias + 512);
    pack_kernel<<<768, 256, 0, stream>>>(W(1,0,0), W(1,0,1), 256, 8, 196608, wsH + p1f, W(1,0,2), W(1,0,3), bias + 1024);
    pack_kernel<<<768, 256, 0, stream>>>(W(1,1,0), W(1,1,1), 256, 8, 196608, wsH + p1b, W(1,1,2), W(1,1,3), bias + 1536);
    pack_kernel<<<768, 256, 0, stream>>>(W(2,0,0), W(2,0,1), 256, 8, 196608, wsH + p2f, W(2,0,2), W(2,0,3), bias + 2048);
    pack_kernel<<<768, 256, 0, stream>>>(W(2,1,0), W(2,1,1), 256, 8, 196608, wsH + p2b, W(2,1,2), W(2,1,3), bias + 2560);

    // ---- pick batch chunking so 2 fp16 y-buffers fit in remaining ws ----
    const size_t avail_halfs = (ws_size > head_bytes) ? (ws_size - head_bytes) / 2 : 0;
    int chunks = 1;
    while (chunks < 128 && (size_t)2 * (B_ / chunks) * 15360 > avail_halfs) chunks *= 2;
    const int CB = B_ / chunks;

    _Float16* yA = y0;
    _Float16* yB = y0 + (size_t)CB * 15360;

    for (int c = 0; c < chunks; ++c) {
        const float* xc = x + (size_t)c * CB * (L_ * I_);
        float* outc = (float*)d_out + (size_t)c * CB * 2;
        lstm_mfma<1, 5, 3, 1><<<2 * CB / 32, 512, SMEM_BYTES, stream>>>(
            xc, nullptr, wsH + p0f, wsH + p0b, bias + 0, bias + 512, yA);
        lstm_mfma<8, 12, 6, 0><<<2 * CB / 32, 512, SMEM_BYTES, stream>>>(
            nullptr, yA, wsH + p1f, wsH + p1b, bias + 1024, bias + 1536, yB);
        lstm_mfma<8, 12, 6, 0><<<2 * CB / 32, 512, SMEM_BYTES, stream>>>(
            nullptr, yB, wsH + p2f, wsH + p2b, bias + 2048, bias + 2560, yA);
        final_kernel<<<(CB + 3) / 4, 256, 0, stream>>>(yA, w_out, b_out, outc, CB);
    }
}